// Round 13
// baseline (25.737 us; speedup 1.0000x reference)
//
#include <hip/hip_runtime.h>
#include <hip/hip_bf16.h>
#include <math.h>

typedef __attribute__((ext_vector_type(8))) short bf16x8;
typedef __attribute__((ext_vector_type(4))) float f32x4;

constexpr int BD = 1024;
constexpr float EPS = 1e-3f;
// d_ws layout
constexpr int WB_MAIN = 32 * 5 * 64 * 8 * 2;    // 163840  [32 ksteps][5 tiles][64 lanes][8 bf16]
constexpr int WB2_OFF = WB_MAIN;                 // w2 frags: 6*64*8*2 = 6144
constexpr int WB3_OFF = WB2_OFF + 6144;          // w3 frags: 4*64*8*2 = 4096
constexpr int CST_OFF = WB3_OFF + 4096;          // 3 floats

__device__ __forceinline__ float wave_allsum(float v) {
#pragma unroll
    for (int m = 1; m < 64; m <<= 1) v += __shfl_xor(v, m, 64);
    return v;
}
__device__ __forceinline__ unsigned short f2bf(float f) {
    __hip_bfloat16 h = __float2bfloat16(f);   // RNE
    unsigned short u; __builtin_memcpy(&u, &h, 2);
    return u;
}
__device__ __forceinline__ float bf2f(unsigned short u) {
    return __uint_as_float(((unsigned)u) << 16);
}
// 2 floats -> packed bf16x2 (RNE), single HW instruction on gfx950
__device__ __forceinline__ unsigned cvt_pk_bf16(float lo, float hi) {
    unsigned r;
    asm("v_cvt_pk_bf16_f32 %0, %1, %2" : "=v"(r) : "v"(lo), "v"(hi));
    return r;
}
__device__ __forceinline__ float tanh_fast(float x) {
    const float xc = fminf(fmaxf(x, -15.f), 15.f);
    const float e = __expf(2.f * xc);
    return (e - 1.f) * __builtin_amdgcn_rcpf(e + 1.f);
}
__device__ __forceinline__ float sigmoid_fast(float z) {
    return __builtin_amdgcn_rcpf(1.f + __expf(-z));
}

// ---------------- prep: bf16 B-fragments (w1+cross, w2, w3) + cross constants ----------------
__global__ void dcn_prep(const float* __restrict__ w1,
                         const float* __restrict__ cross_w,
                         const float* __restrict__ cross_b,
                         const float* __restrict__ w_out,
                         const float* __restrict__ w2,
                         const float* __restrict__ w3,
                         unsigned short* __restrict__ ws) {
    const int bx = blockIdx.x;
    if (bx == 40) {                       // cross constants
        if (threadIdx.x < 64) {
            const int l = threadIdx.x;
            float q2 = 0.f, q3 = 0.f, Cc = 0.f;
            for (int j = 0; j < 16; ++j) {
                const int k = l * 16 + j;
                const float c0 = cross_b[k], c1 = cross_b[BD + k], c2 = cross_b[2 * BD + k];
                q2 += c0 * cross_w[BD + k];
                q3 += (c0 + c1) * cross_w[2 * BD + k];
                Cc += (c0 + c1 + c2) * w_out[k];
            }
            q2 = wave_allsum(q2); q3 = wave_allsum(q3); Cc = wave_allsum(Cc);
            float* consts = (float*)((char*)ws + CST_OFF);
            if (l == 0) { consts[0] = q2; consts[1] = q3; consts[2] = Cc; }
        }
        return;
    }
    if (bx < 40) {                        // main-GEMM fragments
        const int idx = bx * 256 + threadIdx.x;   // [0, 10240)
        const int g = idx / 320;          // k-step 0..31
        const int rem = idx - g * 320;
        const int t = rem >> 6;           // tile 0..4
        const int l = rem & 63;
        const int c = l & 15;
        const int k0 = g * 32 + (l >> 4) * 8;
        unsigned short o[8] __attribute__((aligned(16)));
#pragma unroll
        for (int j = 0; j < 8; ++j) {
            const int k = k0 + j;
            unsigned short r;
            if (t < 4) {
                r = f2bf(w1[k * 64 + t * 16 + c]);
            } else if (c < 8) {
                const int vsel = c & 3;
                const float v = (vsel < 3) ? cross_w[vsel * BD + k] : w_out[k];
                const unsigned short h = f2bf(v);
                r = (c < 4) ? h : f2bf(v - bf2f(h));
            } else {
                r = 0;
            }
            o[j] = r;
        }
        *(uint4*)(ws + (size_t)idx * 8) = *(const uint4*)o;
        return;
    }
    // bx in 41..43 : tower fragments
    const int slot = (bx - 41) * 256 + threadIdx.x;   // [0, 768)
    if (slot < 384) {                     // w2: f = K*3+T, frag [64][8]
        const int f = slot >> 6, l = slot & 63;
        const int K = f / 3, T = f % 3;
        const int kb = K * 32 + (l >> 4) * 8;
        const int col = T * 16 + (l & 15);
        unsigned short o[8] __attribute__((aligned(16)));
#pragma unroll
        for (int j = 0; j < 8; ++j) o[j] = f2bf(w2[(kb + j) * 48 + col]);
        unsigned short* wb2 = (unsigned short*)((char*)ws + WB2_OFF);
        *(uint4*)(wb2 + (size_t)slot * 8) = *(const uint4*)o;
    } else if (slot < 640) {              // w3: f = K*2+T (zero-padded k>=48, col>=24)
        const int s2 = slot - 384;
        const int f = s2 >> 6, l = s2 & 63;
        const int K = f >> 1, T = f & 1;
        const int kb = K * 32 + (l >> 4) * 8;
        const int col = T * 16 + (l & 15);
        unsigned short o[8] __attribute__((aligned(16)));
#pragma unroll
        for (int j = 0; j < 8; ++j) {
            const int k = kb + j;
            o[j] = (k < 48 && col < 24) ? f2bf(w3[k * 24 + col]) : (unsigned short)0;
        }
        unsigned short* wb3 = (unsigned short*)((char*)ws + WB3_OFF);
        *(uint4*)(wb3 + (size_t)s2 * 8) = *(const uint4*)o;
    }
}

// ---------------- main: 32-row tile, 2 waves split K, parallel 16-row epilogues ----------------
__global__ __launch_bounds__(128, 2) void dcn_main(
    const float* __restrict__ x,
    const unsigned short* __restrict__ wbm,
    const unsigned short* __restrict__ w2f,
    const unsigned short* __restrict__ w3f,
    const float* __restrict__ consts,
    const float* __restrict__ b1, const float* __restrict__ g1,
    const float* __restrict__ be1, const float* __restrict__ m1, const float* __restrict__ v1,
    const float* __restrict__ b2, const float* __restrict__ g2,
    const float* __restrict__ be2, const float* __restrict__ m2, const float* __restrict__ v2,
    const float* __restrict__ b3, const float* __restrict__ g3,
    const float* __restrict__ be3, const float* __restrict__ m3, const float* __restrict__ v3,
    const float* __restrict__ w_out, const float* __restrict__ b_out,
    float* __restrict__ out)
{
    // LDS: PK0 [5KB] | PK1 [5KB] | H1 x2 [8704] | H2 x2 [8704] | LC x2 [512]
    __shared__ char sb[28160] __attribute__((aligned(16)));

    const int tid = threadIdx.x;
    const int l = tid & 63;               // lane
    const int w = tid >> 6;               // wave 0/1 = K half
    const int ar = l & 15;                // fragment row
    const int ag = l >> 4;                // k sub-block
    const int gr0 = blockIdx.x * 32;      // 32-row tile

    const int H1 = 10240 + w * 4352;
    const int H2 = 18944 + w * 4352;
    const int LC = 27648 + w * 256;

    // per-lane A sources: group a = rows gr0..+15, group b = rows gr0+16..+31
    const float* xb0 = x + (size_t)(gr0 + ar) * BD + w * 512 + ag * 8;
    const float* xb1 = xb0 + (size_t)16 * BD;

    // B fragments for this wave's k-steps g = w*16 + s
    const bf16x8* bb = (const bf16x8*)wbm + (size_t)(w * 16 * 5) * 64 + l;

    // ---- prologue: A 4-deep (both groups), B 2-deep ----
    float4 Aa0[4], Aa1[4], Ab0[4], Ab1[4];
#pragma unroll
    for (int s = 0; s < 4; ++s) {
        Aa0[s] = *(const float4*)(xb0 + s * 32);
        Aa1[s] = *(const float4*)(xb0 + s * 32 + 4);
        Ab0[s] = *(const float4*)(xb1 + s * 32);
        Ab1[s] = *(const float4*)(xb1 + s * 32 + 4);
    }
    bf16x8 Bf[2][5];
#pragma unroll
    for (int s = 0; s < 2; ++s)
#pragma unroll
        for (int t = 0; t < 5; ++t) Bf[s][t] = bb[(s * 5 + t) * 64];

    f32x4 z4 = {0.f,0.f,0.f,0.f};
    f32x4 a0 = z4, a1 = z4, a2_ = z4, a3_ = z4, a4 = z4;   // rows 0-15 half
    f32x4 b0 = z4, b1_ = z4, b2_ = z4, b3_ = z4, b4 = z4;  // rows 16-31 half

#define CVTPAIR(VA0, VA1, XH, XL) do {                                          \
    XH.u[0] = cvt_pk_bf16(VA0.x, VA0.y);                                        \
    XH.u[1] = cvt_pk_bf16(VA0.z, VA0.w);                                        \
    XH.u[2] = cvt_pk_bf16(VA1.x, VA1.y);                                        \
    XH.u[3] = cvt_pk_bf16(VA1.z, VA1.w);                                        \
    const float t0_ = VA0.x - __uint_as_float(XH.u[0] << 16);                   \
    const float t1_ = VA0.y - __uint_as_float(XH.u[0] & 0xFFFF0000u);           \
    const float t2_ = VA0.z - __uint_as_float(XH.u[1] << 16);                   \
    const float t3_ = VA0.w - __uint_as_float(XH.u[1] & 0xFFFF0000u);           \
    const float t4_ = VA1.x - __uint_as_float(XH.u[2] << 16);                   \
    const float t5_ = VA1.y - __uint_as_float(XH.u[2] & 0xFFFF0000u);           \
    const float t6_ = VA1.z - __uint_as_float(XH.u[3] << 16);                   \
    const float t7_ = VA1.w - __uint_as_float(XH.u[3] & 0xFFFF0000u);           \
    XL.u[0] = cvt_pk_bf16(t0_, t1_);                                            \
    XL.u[1] = cvt_pk_bf16(t2_, t3_);                                            \
    XL.u[2] = cvt_pk_bf16(t4_, t5_);                                            \
    XL.u[3] = cvt_pk_bf16(t6_, t7_);                                            \
} while (0)

#pragma unroll
    for (int s = 0; s < 16; ++s) {
        const float4 va0 = Aa0[s & 3], va1 = Aa1[s & 3];
        const float4 vb0 = Ab0[s & 3], vb1 = Ab1[s & 3];
        if (s < 12) {   // reload slot for step s+4
            Aa0[s & 3] = *(const float4*)(xb0 + (s + 4) * 32);
            Aa1[s & 3] = *(const float4*)(xb0 + (s + 4) * 32 + 4);
            Ab0[s & 3] = *(const float4*)(xb1 + (s + 4) * 32);
            Ab1[s & 3] = *(const float4*)(xb1 + (s + 4) * 32 + 4);
        }
        const bf16x8 B0 = Bf[s & 1][0], B1 = Bf[s & 1][1], B2 = Bf[s & 1][2],
                     B3 = Bf[s & 1][3], B4 = Bf[s & 1][4];
        if (s + 2 < 16) {
#pragma unroll
            for (int t = 0; t < 5; ++t) Bf[s & 1][t] = bb[((s + 2) * 5 + t) * 64];
        }
        union { unsigned u[4]; bf16x8 v; } XHa, XLa, XHb, XLb;
        CVTPAIR(va0, va1, XHa, XLa);
        CVTPAIR(vb0, vb1, XHb, XLb);

        a0  = __builtin_amdgcn_mfma_f32_16x16x32_bf16(XHa.v, B0, a0, 0, 0, 0);
        b0  = __builtin_amdgcn_mfma_f32_16x16x32_bf16(XHb.v, B0, b0, 0, 0, 0);
        a1  = __builtin_amdgcn_mfma_f32_16x16x32_bf16(XHa.v, B1, a1, 0, 0, 0);
        b1_ = __builtin_amdgcn_mfma_f32_16x16x32_bf16(XHb.v, B1, b1_, 0, 0, 0);
        a2_ = __builtin_amdgcn_mfma_f32_16x16x32_bf16(XHa.v, B2, a2_, 0, 0, 0);
        b2_ = __builtin_amdgcn_mfma_f32_16x16x32_bf16(XHb.v, B2, b2_, 0, 0, 0);
        a3_ = __builtin_amdgcn_mfma_f32_16x16x32_bf16(XHa.v, B3, a3_, 0, 0, 0);
        b3_ = __builtin_amdgcn_mfma_f32_16x16x32_bf16(XHb.v, B3, b3_, 0, 0, 0);
        a4  = __builtin_amdgcn_mfma_f32_16x16x32_bf16(XHa.v, B4, a4, 0, 0, 0);
        a4  = __builtin_amdgcn_mfma_f32_16x16x32_bf16(XLa.v, B4, a4, 0, 0, 0);
        b4  = __builtin_amdgcn_mfma_f32_16x16x32_bf16(XHb.v, B4, b4, 0, 0, 0);
        b4  = __builtin_amdgcn_mfma_f32_16x16x32_bf16(XLb.v, B4, b4, 0, 0, 0);
    }
#undef CVTPAIR

    // ---- split-K combine: each wave parks the half it does NOT own ----
    // wave 0 owns rows 0-15 (a); wave 1 owns rows 16-31 (b).
    const int pkMine = w * 5120;
    const int pkOther = 5120 - pkMine;
    if (w == 0) {
        *(f32x4*)&sb[pkMine + 0 * 1024 + l * 16] = b0;
        *(f32x4*)&sb[pkMine + 1 * 1024 + l * 16] = b1_;
        *(f32x4*)&sb[pkMine + 2 * 1024 + l * 16] = b2_;
        *(f32x4*)&sb[pkMine + 3 * 1024 + l * 16] = b3_;
        *(f32x4*)&sb[pkMine + 4 * 1024 + l * 16] = b4;
    } else {
        *(f32x4*)&sb[pkMine + 0 * 1024 + l * 16] = a0;
        *(f32x4*)&sb[pkMine + 1 * 1024 + l * 16] = a1;
        *(f32x4*)&sb[pkMine + 2 * 1024 + l * 16] = a2_;
        *(f32x4*)&sb[pkMine + 3 * 1024 + l * 16] = a3_;
        *(f32x4*)&sb[pkMine + 4 * 1024 + l * 16] = a4;
    }
    __syncthreads();
    f32x4 acc0, acc1, acc2, acc3, acc4;
    if (w == 0) {
        acc0 = a0;  acc1 = a1;  acc2 = a2_; acc3 = a3_; acc4 = a4;
    } else {
        acc0 = b0;  acc1 = b1_; acc2 = b2_; acc3 = b3_; acc4 = b4;
    }
    acc0 += *(const f32x4*)&sb[pkOther + 0 * 1024 + l * 16];
    acc1 += *(const f32x4*)&sb[pkOther + 1 * 1024 + l * 16];
    acc2 += *(const f32x4*)&sb[pkOther + 2 * 1024 + l * 16];
    acc3 += *(const f32x4*)&sb[pkOther + 3 * 1024 + l * 16];
    acc4 += *(const f32x4*)&sb[pkOther + 4 * 1024 + l * 16];

    // ---- epilogue: wave w handles rows gr0 + w*16 .. +15 (intra-wave only) ----
    const int myrow0 = gr0 + w * 16;

    const bf16x8* w2b = (const bf16x8*)w2f + l;
    bf16x8 W2[6];
#pragma unroll
    for (int f = 0; f < 6; ++f) W2[f] = w2b[f * 64];
    const bf16x8* w3b = (const bf16x8*)w3f + l;
    bf16x8 W3[4];
#pragma unroll
    for (int f = 0; f < 4; ++f) W3[f] = w3b[f * 64];

    const float q2c = consts[0], q3c = consts[1], Ccc = consts[2];
    const float bo = b_out[0];
    const float wo0 = w_out[1024 + ar];
    const float wo1 = (ar < 8) ? w_out[1040 + ar] : 0.f;
    float b1p[4], g1p[4], be1p[4], m1p[4], iv1p[4];
#pragma unroll
    for (int t = 0; t < 4; ++t) {
        const int c = t * 16 + ar;
        b1p[t] = b1[c]; g1p[t] = g1[c]; be1p[t] = be1[c]; m1p[t] = m1[c];
        iv1p[t] = rsqrtf(v1[c] + EPS);
    }
    float b2p[3], g2p[3], be2p[3], m2p[3], iv2p[3];
#pragma unroll
    for (int t = 0; t < 3; ++t) {
        const int c = t * 16 + ar;
        b2p[t] = b2[c]; g2p[t] = g2[c]; be2p[t] = be2[c]; m2p[t] = m2[c];
        iv2p[t] = rsqrtf(v2[c] + EPS);
    }
    float b3p[2], g3p[2], be3p[2], m3p[2], iv3p[2];
#pragma unroll
    for (int t = 0; t < 2; ++t) {
        const int c = t == 0 ? ar : (16 + ar < 24 ? 16 + ar : 23);
        b3p[t] = b3[c]; g3p[t] = g3[c]; be3p[t] = be3[c]; m3p[t] = m3[c];
        iv3p[t] = rsqrtf(v3[c] + EPS);
    }

    // cross scalars: fold lo cols (4..7) into hi (0..3), park per-row in LDS
    {
        f32x4 p4 = acc4;
#pragma unroll
        for (int q = 0; q < 4; ++q) p4[q] += __shfl_xor(acc4[q], 4, 64);
        if (ar < 4) {
#pragma unroll
            for (int q = 0; q < 4; ++q)
                *(float*)&sb[LC + ((ag * 4 + q) * 4 + ar) * 4] = p4[q];
        }
    }

    // BN1 + relu, write h1 tile [16 rows][64 cols] f32, row stride 272B
    {
        const f32x4 av[4] = {acc0, acc1, acc2, acc3};
#pragma unroll
        for (int t = 0; t < 4; ++t) {
            const int c = t * 16 + ar;
#pragma unroll
            for (int q = 0; q < 4; ++q) {
                const float y = fmaxf(av[t][q] + b1p[t], 0.f);
                const float h = fmaf(g1p[t] * (y - m1p[t]), iv1p[t], be1p[t]);
                *(float*)&sb[H1 + (ag * 4 + q) * 272 + c * 4] = h;
            }
        }
    }
    // zero-fill h2 cols 48..63 (finite garbage guard for layer-3 A)
    {
        *(f32x4*)&sb[H2 + ar * 272 + 192 + ag * 16] = z4;
    }

    // layer 2: h1 -> (tanh,BN) -> h2   via MFMA
    bf16x8 a2f[2];
#pragma unroll
    for (int K = 0; K < 2; ++K) {
        const float4 f0 = *(const float4*)&sb[H1 + ar * 272 + (K * 32 + ag * 8) * 4];
        const float4 f1 = *(const float4*)&sb[H1 + ar * 272 + (K * 32 + ag * 8) * 4 + 16];
        union { unsigned u[4]; bf16x8 v; } P;
        P.u[0] = cvt_pk_bf16(f0.x, f0.y);
        P.u[1] = cvt_pk_bf16(f0.z, f0.w);
        P.u[2] = cvt_pk_bf16(f1.x, f1.y);
        P.u[3] = cvt_pk_bf16(f1.z, f1.w);
        a2f[K] = P.v;
    }
    f32x4 c2t[3] = {z4, z4, z4};
#pragma unroll
    for (int K = 0; K < 2; ++K) {
        c2t[0] = __builtin_amdgcn_mfma_f32_16x16x32_bf16(a2f[K], W2[K * 3 + 0], c2t[0], 0, 0, 0);
        c2t[1] = __builtin_amdgcn_mfma_f32_16x16x32_bf16(a2f[K], W2[K * 3 + 1], c2t[1], 0, 0, 0);
        c2t[2] = __builtin_amdgcn_mfma_f32_16x16x32_bf16(a2f[K], W2[K * 3 + 2], c2t[2], 0, 0, 0);
    }
#pragma unroll
    for (int t = 0; t < 3; ++t) {
        const int c = t * 16 + ar;
#pragma unroll
        for (int q = 0; q < 4; ++q) {
            const float th = tanh_fast(c2t[t][q] + b2p[t]);
            const float h = fmaf(g2p[t] * (th - m2p[t]), iv2p[t], be2p[t]);
            *(float*)&sb[H2 + (ag * 4 + q) * 272 + c * 4] = h;
        }
    }

    // layer 3: h2 -> (tanh,BN) -> h3   via MFMA (w3 zero-padded handles k/col tails)
    bf16x8 a3f[2];
#pragma unroll
    for (int K = 0; K < 2; ++K) {
        const float4 f0 = *(const float4*)&sb[H2 + ar * 272 + (K * 32 + ag * 8) * 4];
        const float4 f1 = *(const float4*)&sb[H2 + ar * 272 + (K * 32 + ag * 8) * 4 + 16];
        union { unsigned u[4]; bf16x8 v; } P;
        P.u[0] = cvt_pk_bf16(f0.x, f0.y);
        P.u[1] = cvt_pk_bf16(f0.z, f0.w);
        P.u[2] = cvt_pk_bf16(f1.x, f1.y);
        P.u[3] = cvt_pk_bf16(f1.z, f1.w);
        a3f[K] = P.v;
    }
    f32x4 c3t[2] = {z4, z4};
#pragma unroll
    for (int K = 0; K < 2; ++K) {
        c3t[0] = __builtin_amdgcn_mfma_f32_16x16x32_bf16(a3f[K], W3[K * 2 + 0], c3t[0], 0, 0, 0);
        c3t[1] = __builtin_amdgcn_mfma_f32_16x16x32_bf16(a3f[K], W3[K * 2 + 1], c3t[1], 0, 0, 0);
    }
    // tanh+BN3, weighted col-sum (wo1=0 masks cols>=24), 16-lane tree reduce
    float contrib[4];
#pragma unroll
    for (int q = 0; q < 4; ++q) {
        const float t0 = tanh_fast(c3t[0][q] + b3p[0]);
        const float h0 = fmaf(g3p[0] * (t0 - m3p[0]), iv3p[0], be3p[0]);
        const float t1 = tanh_fast(c3t[1][q] + b3p[1]);
        const float h1v = fmaf(g3p[1] * (t1 - m3p[1]), iv3p[1], be3p[1]);
        contrib[q] = h0 * wo0 + h1v * wo1;
    }
#pragma unroll
    for (int m = 1; m < 16; m <<= 1) {
#pragma unroll
        for (int q = 0; q < 4; ++q) contrib[q] += __shfl_xor(contrib[q], m, 64);
    }

    // cross recurrence + sigmoid + store (lane ar==q writes row ag*4+q)
#pragma unroll
    for (int q = 0; q < 4; ++q) {
        const f32x4 pr = *(const f32x4*)&sb[LC + (ag * 4 + q) * 16];
        const float p1 = pr[0], p2 = pr[1], p3 = pr[2], d0 = pr[3];
        const float s1 = p1;
        const float s2 = fmaf(1.f + s1, p2, q2c);
        const float s3 = fmaf(1.f + s1 + s2, p3, q3c);
        const float alpha = 1.f + s1 + s2 + s3;
        const float z = fmaf(alpha, d0, Ccc) + contrib[q] + bo;
        const float o = sigmoid_fast(z);
        if (ar == q) out[myrow0 + ag * 4 + q] = o;
    }
}

extern "C" void kernel_launch(void* const* d_in, const int* in_sizes, int n_in,
                              void* d_out, int out_size, void* d_ws, size_t ws_size,
                              hipStream_t stream) {
    const float* x       = (const float*)d_in[0];
    const float* cross_w = (const float*)d_in[1];
    const float* cross_b = (const float*)d_in[2];
    const float* w1      = (const float*)d_in[3];
    const float* b1      = (const float*)d_in[4];
    const float* g1      = (const float*)d_in[5];
    const float* be1     = (const float*)d_in[6];
    const float* m1      = (const float*)d_in[7];
    const float* v1      = (const float*)d_in[8];
    const float* w2      = (const float*)d_in[9];
    const float* b2      = (const float*)d_in[10];
    const float* g2      = (const float*)d_in[11];
    const float* be2     = (const float*)d_in[12];
    const float* m2      = (const float*)d_in[13];
    const float* v2      = (const float*)d_in[14];
    const float* w3      = (const float*)d_in[15];
    const float* b3      = (const float*)d_in[16];
    const float* g3      = (const float*)d_in[17];
    const float* be3     = (const float*)d_in[18];
    const float* m3      = (const float*)d_in[19];
    const float* v3      = (const float*)d_in[20];
    const float* w_out   = (const float*)d_in[21];
    const float* b_out   = (const float*)d_in[22];
    float* out = (float*)d_out;

    unsigned short* ws = (unsigned short*)d_ws;
    const unsigned short* w2f = (const unsigned short*)((char*)d_ws + WB2_OFF);
    const unsigned short* w3f = (const unsigned short*)((char*)d_ws + WB3_OFF);
    const float* consts = (const float*)((char*)d_ws + CST_OFF);

    dcn_prep<<<44, 256, 0, stream>>>(w1, cross_w, cross_b, w_out, w2, w3, ws);
    dcn_main<<<512, 128, 0, stream>>>(x, ws, w2f, w3f, consts,
                                      b1, g1, be1, m1, v1,
                                      b2, g2, be2, m2, v2,
                                      b3, g3, be3, m3, v3,
                                      w_out, b_out, out);
}

// Round 14
// 25.622 us; speedup vs baseline: 1.0045x; 1.0045x over previous
//
#include <hip/hip_runtime.h>
#include <hip/hip_bf16.h>
#include <math.h>

typedef __attribute__((ext_vector_type(8))) short bf16x8;
typedef __attribute__((ext_vector_type(4))) float f32x4;

constexpr int BD = 1024;
constexpr float EPS = 1e-3f;
// d_ws layout
constexpr int WB_MAIN = 32 * 5 * 64 * 8 * 2;    // 163840  [32 ksteps][5 tiles][64 lanes][8 bf16]
constexpr int WB2_OFF = WB_MAIN;                 // w2 frags: 6*64*8*2 = 6144
constexpr int WB3_OFF = WB2_OFF + 6144;          // w3 frags: 4*64*8*2 = 4096
constexpr int CST_OFF = WB3_OFF + 4096;          // 3 floats

__device__ __forceinline__ float wave_allsum(float v) {
#pragma unroll
    for (int m = 1; m < 64; m <<= 1) v += __shfl_xor(v, m, 64);
    return v;
}
__device__ __forceinline__ unsigned short f2bf(float f) {
    __hip_bfloat16 h = __float2bfloat16(f);   // RNE
    unsigned short u; __builtin_memcpy(&u, &h, 2);
    return u;
}
__device__ __forceinline__ float bf2f(unsigned short u) {
    return __uint_as_float(((unsigned)u) << 16);
}
// 2 floats -> packed bf16x2 (RNE), single HW instruction on gfx950
__device__ __forceinline__ unsigned cvt_pk_bf16(float lo, float hi) {
    unsigned r;
    asm("v_cvt_pk_bf16_f32 %0, %1, %2" : "=v"(r) : "v"(lo), "v"(hi));
    return r;
}
__device__ __forceinline__ float tanh_fast(float x) {
    const float xc = fminf(fmaxf(x, -15.f), 15.f);
    const float e = __expf(2.f * xc);
    return (e - 1.f) * __builtin_amdgcn_rcpf(e + 1.f);
}
__device__ __forceinline__ float sigmoid_fast(float z) {
    return __builtin_amdgcn_rcpf(1.f + __expf(-z));
}

// ---------------- prep: bf16 B-fragments (w1+cross, w2, w3) + cross constants ----------------
__global__ void dcn_prep(const float* __restrict__ w1,
                         const float* __restrict__ cross_w,
                         const float* __restrict__ cross_b,
                         const float* __restrict__ w_out,
                         const float* __restrict__ w2,
                         const float* __restrict__ w3,
                         unsigned short* __restrict__ ws) {
    const int bx = blockIdx.x;
    if (bx == 40) {                       // cross constants
        if (threadIdx.x < 64) {
            const int l = threadIdx.x;
            float q2 = 0.f, q3 = 0.f, Cc = 0.f;
            for (int j = 0; j < 16; ++j) {
                const int k = l * 16 + j;
                const float c0 = cross_b[k], c1 = cross_b[BD + k], c2 = cross_b[2 * BD + k];
                q2 += c0 * cross_w[BD + k];
                q3 += (c0 + c1) * cross_w[2 * BD + k];
                Cc += (c0 + c1 + c2) * w_out[k];
            }
            q2 = wave_allsum(q2); q3 = wave_allsum(q3); Cc = wave_allsum(Cc);
            float* consts = (float*)((char*)ws + CST_OFF);
            if (l == 0) { consts[0] = q2; consts[1] = q3; consts[2] = Cc; }
        }
        return;
    }
    if (bx < 40) {                        // main-GEMM fragments
        const int idx = bx * 256 + threadIdx.x;   // [0, 10240)
        const int g = idx / 320;          // k-step 0..31
        const int rem = idx - g * 320;
        const int t = rem >> 6;           // tile 0..4
        const int l = rem & 63;
        const int c = l & 15;
        const int k0 = g * 32 + (l >> 4) * 8;
        unsigned short o[8] __attribute__((aligned(16)));
#pragma unroll
        for (int j = 0; j < 8; ++j) {
            const int k = k0 + j;
            unsigned short r;
            if (t < 4) {
                r = f2bf(w1[k * 64 + t * 16 + c]);
            } else if (c < 8) {
                const int vsel = c & 3;
                const float v = (vsel < 3) ? cross_w[vsel * BD + k] : w_out[k];
                const unsigned short h = f2bf(v);
                r = (c < 4) ? h : f2bf(v - bf2f(h));
            } else {
                r = 0;
            }
            o[j] = r;
        }
        *(uint4*)(ws + (size_t)idx * 8) = *(const uint4*)o;
        return;
    }
    // bx in 41..43 : tower fragments
    const int slot = (bx - 41) * 256 + threadIdx.x;   // [0, 768)
    if (slot < 384) {                     // w2: f = K*3+T, frag [64][8]
        const int f = slot >> 6, l = slot & 63;
        const int K = f / 3, T = f % 3;
        const int kb = K * 32 + (l >> 4) * 8;
        const int col = T * 16 + (l & 15);
        unsigned short o[8] __attribute__((aligned(16)));
#pragma unroll
        for (int j = 0; j < 8; ++j) o[j] = f2bf(w2[(kb + j) * 48 + col]);
        unsigned short* wb2 = (unsigned short*)((char*)ws + WB2_OFF);
        *(uint4*)(wb2 + (size_t)slot * 8) = *(const uint4*)o;
    } else if (slot < 640) {              // w3: f = K*2+T (zero-padded k>=48, col>=24)
        const int s2 = slot - 384;
        const int f = s2 >> 6, l = s2 & 63;
        const int K = f >> 1, T = f & 1;
        const int kb = K * 32 + (l >> 4) * 8;
        const int col = T * 16 + (l & 15);
        unsigned short o[8] __attribute__((aligned(16)));
#pragma unroll
        for (int j = 0; j < 8; ++j) {
            const int k = kb + j;
            o[j] = (k < 48 && col < 24) ? f2bf(w3[k * 24 + col]) : (unsigned short)0;
        }
        unsigned short* wb3 = (unsigned short*)((char*)ws + WB3_OFF);
        *(uint4*)(wb3 + (size_t)s2 * 8) = *(const uint4*)o;
    }
}

// ---------------- main: 32-row tile, 2 waves split K, A-prefetch 6-deep ----------------
__global__ __launch_bounds__(128, 2) void dcn_main(
    const float* __restrict__ x,
    const unsigned short* __restrict__ wbm,
    const unsigned short* __restrict__ w2f,
    const unsigned short* __restrict__ w3f,
    const float* __restrict__ consts,
    const float* __restrict__ b1, const float* __restrict__ g1,
    const float* __restrict__ be1, const float* __restrict__ m1, const float* __restrict__ v1,
    const float* __restrict__ b2, const float* __restrict__ g2,
    const float* __restrict__ be2, const float* __restrict__ m2, const float* __restrict__ v2,
    const float* __restrict__ b3, const float* __restrict__ g3,
    const float* __restrict__ be3, const float* __restrict__ m3, const float* __restrict__ v3,
    const float* __restrict__ w_out, const float* __restrict__ b_out,
    float* __restrict__ out)
{
    // LDS: PK0 [5KB] | PK1 [5KB] | H1 x2 [8704] | H2 x2 [8704] | LC x2 [512]
    __shared__ char sb[28160] __attribute__((aligned(16)));

    const int tid = threadIdx.x;
    const int l = tid & 63;               // lane
    const int w = tid >> 6;               // wave 0/1 = K half
    const int ar = l & 15;                // fragment row
    const int ag = l >> 4;                // k sub-block
    const int gr0 = blockIdx.x * 32;      // 32-row tile

    const int H1 = 10240 + w * 4352;
    const int H2 = 18944 + w * 4352;
    const int LC = 27648 + w * 256;

    // per-lane A sources: group a = rows gr0..+15, group b = rows gr0+16..+31
    const float* xb0 = x + (size_t)(gr0 + ar) * BD + w * 512 + ag * 8;
    const float* xb1 = xb0 + (size_t)16 * BD;

    // B fragments for this wave's k-steps g = w*16 + s
    const bf16x8* bb = (const bf16x8*)wbm + (size_t)(w * 16 * 5) * 64 + l;

    // ---- prologue: A 6-deep (both groups), B 2-deep ----
    float4 Aa0[6], Aa1[6], Ab0[6], Ab1[6];
#pragma unroll
    for (int s = 0; s < 6; ++s) {
        Aa0[s] = *(const float4*)(xb0 + s * 32);
        Aa1[s] = *(const float4*)(xb0 + s * 32 + 4);
        Ab0[s] = *(const float4*)(xb1 + s * 32);
        Ab1[s] = *(const float4*)(xb1 + s * 32 + 4);
    }
    bf16x8 Bf[2][5];
#pragma unroll
    for (int s = 0; s < 2; ++s)
#pragma unroll
        for (int t = 0; t < 5; ++t) Bf[s][t] = bb[(s * 5 + t) * 64];

    f32x4 z4 = {0.f,0.f,0.f,0.f};
    f32x4 a0 = z4, a1 = z4, a2_ = z4, a3_ = z4, a4 = z4;   // rows 0-15 half
    f32x4 b0 = z4, b1_ = z4, b2_ = z4, b3_ = z4, b4 = z4;  // rows 16-31 half

#define CVTPAIR(VA0, VA1, XH, XL) do {                                          \
    XH.u[0] = cvt_pk_bf16(VA0.x, VA0.y);                                        \
    XH.u[1] = cvt_pk_bf16(VA0.z, VA0.w);                                        \
    XH.u[2] = cvt_pk_bf16(VA1.x, VA1.y);                                        \
    XH.u[3] = cvt_pk_bf16(VA1.z, VA1.w);                                        \
    const float t0_ = VA0.x - __uint_as_float(XH.u[0] << 16);                   \
    const float t1_ = VA0.y - __uint_as_float(XH.u[0] & 0xFFFF0000u);           \
    const float t2_ = VA0.z - __uint_as_float(XH.u[1] << 16);                   \
    const float t3_ = VA0.w - __uint_as_float(XH.u[1] & 0xFFFF0000u);           \
    const float t4_ = VA1.x - __uint_as_float(XH.u[2] << 16);                   \
    const float t5_ = VA1.y - __uint_as_float(XH.u[2] & 0xFFFF0000u);           \
    const float t6_ = VA1.z - __uint_as_float(XH.u[3] << 16);                   \
    const float t7_ = VA1.w - __uint_as_float(XH.u[3] & 0xFFFF0000u);           \
    XL.u[0] = cvt_pk_bf16(t0_, t1_);                                            \
    XL.u[1] = cvt_pk_bf16(t2_, t3_);                                            \
    XL.u[2] = cvt_pk_bf16(t4_, t5_);                                            \
    XL.u[3] = cvt_pk_bf16(t6_, t7_);                                            \
} while (0)

#pragma unroll
    for (int s = 0; s < 16; ++s) {
        const int sl = s % 6;
        const float4 va0 = Aa0[sl], va1 = Aa1[sl];
        const float4 vb0 = Ab0[sl], vb1 = Ab1[sl];
        if (s < 10) {   // reload slot for step s+6
            Aa0[sl] = *(const float4*)(xb0 + (s + 6) * 32);
            Aa1[sl] = *(const float4*)(xb0 + (s + 6) * 32 + 4);
            Ab0[sl] = *(const float4*)(xb1 + (s + 6) * 32);
            Ab1[sl] = *(const float4*)(xb1 + (s + 6) * 32 + 4);
        }
        const bf16x8 B0 = Bf[s & 1][0], B1 = Bf[s & 1][1], B2 = Bf[s & 1][2],
                     B3 = Bf[s & 1][3], B4 = Bf[s & 1][4];
        if (s + 2 < 16) {
#pragma unroll
            for (int t = 0; t < 5; ++t) Bf[s & 1][t] = bb[((s + 2) * 5 + t) * 64];
        }
        union { unsigned u[4]; bf16x8 v; } XHa, XLa, XHb, XLb;
        CVTPAIR(va0, va1, XHa, XLa);
        CVTPAIR(vb0, vb1, XHb, XLb);

        a0  = __builtin_amdgcn_mfma_f32_16x16x32_bf16(XHa.v, B0, a0, 0, 0, 0);
        b0  = __builtin_amdgcn_mfma_f32_16x16x32_bf16(XHb.v, B0, b0, 0, 0, 0);
        a1  = __builtin_amdgcn_mfma_f32_16x16x32_bf16(XHa.v, B1, a1, 0, 0, 0);
        b1_ = __builtin_amdgcn_mfma_f32_16x16x32_bf16(XHb.v, B1, b1_, 0, 0, 0);
        a2_ = __builtin_amdgcn_mfma_f32_16x16x32_bf16(XHa.v, B2, a2_, 0, 0, 0);
        b2_ = __builtin_amdgcn_mfma_f32_16x16x32_bf16(XHb.v, B2, b2_, 0, 0, 0);
        a3_ = __builtin_amdgcn_mfma_f32_16x16x32_bf16(XHa.v, B3, a3_, 0, 0, 0);
        b3_ = __builtin_amdgcn_mfma_f32_16x16x32_bf16(XHb.v, B3, b3_, 0, 0, 0);
        a4  = __builtin_amdgcn_mfma_f32_16x16x32_bf16(XHa.v, B4, a4, 0, 0, 0);
        a4  = __builtin_amdgcn_mfma_f32_16x16x32_bf16(XLa.v, B4, a4, 0, 0, 0);
        b4  = __builtin_amdgcn_mfma_f32_16x16x32_bf16(XHb.v, B4, b4, 0, 0, 0);
        b4  = __builtin_amdgcn_mfma_f32_16x16x32_bf16(XLb.v, B4, b4, 0, 0, 0);
    }
#undef CVTPAIR

    // ---- split-K combine: each wave parks the half it does NOT own ----
    // wave 0 owns rows 0-15 (a); wave 1 owns rows 16-31 (b).
    const int pkMine = w * 5120;
    const int pkOther = 5120 - pkMine;
    if (w == 0) {
        *(f32x4*)&sb[pkMine + 0 * 1024 + l * 16] = b0;
        *(f32x4*)&sb[pkMine + 1 * 1024 + l * 16] = b1_;
        *(f32x4*)&sb[pkMine + 2 * 1024 + l * 16] = b2_;
        *(f32x4*)&sb[pkMine + 3 * 1024 + l * 16] = b3_;
        *(f32x4*)&sb[pkMine + 4 * 1024 + l * 16] = b4;
    } else {
        *(f32x4*)&sb[pkMine + 0 * 1024 + l * 16] = a0;
        *(f32x4*)&sb[pkMine + 1 * 1024 + l * 16] = a1;
        *(f32x4*)&sb[pkMine + 2 * 1024 + l * 16] = a2_;
        *(f32x4*)&sb[pkMine + 3 * 1024 + l * 16] = a3_;
        *(f32x4*)&sb[pkMine + 4 * 1024 + l * 16] = a4;
    }
    __syncthreads();
    f32x4 acc0, acc1, acc2, acc3, acc4;
    if (w == 0) {
        acc0 = a0;  acc1 = a1;  acc2 = a2_; acc3 = a3_; acc4 = a4;
    } else {
        acc0 = b0;  acc1 = b1_; acc2 = b2_; acc3 = b3_; acc4 = b4;
    }
    acc0 += *(const f32x4*)&sb[pkOther + 0 * 1024 + l * 16];
    acc1 += *(const f32x4*)&sb[pkOther + 1 * 1024 + l * 16];
    acc2 += *(const f32x4*)&sb[pkOther + 2 * 1024 + l * 16];
    acc3 += *(const f32x4*)&sb[pkOther + 3 * 1024 + l * 16];
    acc4 += *(const f32x4*)&sb[pkOther + 4 * 1024 + l * 16];

    // ---- epilogue: wave w handles rows gr0 + w*16 .. +15 (intra-wave only) ----
    const int myrow0 = gr0 + w * 16;

    const bf16x8* w2b = (const bf16x8*)w2f + l;
    bf16x8 W2[6];
#pragma unroll
    for (int f = 0; f < 6; ++f) W2[f] = w2b[f * 64];
    const bf16x8* w3b = (const bf16x8*)w3f + l;
    bf16x8 W3[4];
#pragma unroll
    for (int f = 0; f < 4; ++f) W3[f] = w3b[f * 64];

    const float q2c = consts[0], q3c = consts[1], Ccc = consts[2];
    const float bo = b_out[0];
    const float wo0 = w_out[1024 + ar];
    const float wo1 = (ar < 8) ? w_out[1040 + ar] : 0.f;
    float b1p[4], g1p[4], be1p[4], m1p[4], iv1p[4];
#pragma unroll
    for (int t = 0; t < 4; ++t) {
        const int c = t * 16 + ar;
        b1p[t] = b1[c]; g1p[t] = g1[c]; be1p[t] = be1[c]; m1p[t] = m1[c];
        iv1p[t] = rsqrtf(v1[c] + EPS);
    }
    float b2p[3], g2p[3], be2p[3], m2p[3], iv2p[3];
#pragma unroll
    for (int t = 0; t < 3; ++t) {
        const int c = t * 16 + ar;
        b2p[t] = b2[c]; g2p[t] = g2[c]; be2p[t] = be2[c]; m2p[t] = m2[c];
        iv2p[t] = rsqrtf(v2[c] + EPS);
    }
    float b3p[2], g3p[2], be3p[2], m3p[2], iv3p[2];
#pragma unroll
    for (int t = 0; t < 2; ++t) {
        const int c = t == 0 ? ar : (16 + ar < 24 ? 16 + ar : 23);
        b3p[t] = b3[c]; g3p[t] = g3[c]; be3p[t] = be3[c]; m3p[t] = m3[c];
        iv3p[t] = rsqrtf(v3[c] + EPS);
    }

    // cross scalars: fold lo cols (4..7) into hi (0..3), park per-row in LDS
    {
        f32x4 p4 = acc4;
#pragma unroll
        for (int q = 0; q < 4; ++q) p4[q] += __shfl_xor(acc4[q], 4, 64);
        if (ar < 4) {
#pragma unroll
            for (int q = 0; q < 4; ++q)
                *(float*)&sb[LC + ((ag * 4 + q) * 4 + ar) * 4] = p4[q];
        }
    }

    // BN1 + relu, write h1 tile [16 rows][64 cols] f32, row stride 272B
    {
        const f32x4 av[4] = {acc0, acc1, acc2, acc3};
#pragma unroll
        for (int t = 0; t < 4; ++t) {
            const int c = t * 16 + ar;
#pragma unroll
            for (int q = 0; q < 4; ++q) {
                const float y = fmaxf(av[t][q] + b1p[t], 0.f);
                const float h = fmaf(g1p[t] * (y - m1p[t]), iv1p[t], be1p[t]);
                *(float*)&sb[H1 + (ag * 4 + q) * 272 + c * 4] = h;
            }
        }
    }
    // zero-fill h2 cols 48..63 (finite garbage guard for layer-3 A)
    {
        *(f32x4*)&sb[H2 + ar * 272 + 192 + ag * 16] = z4;
    }

    // layer 2: h1 -> (tanh,BN) -> h2   via MFMA
    bf16x8 a2f[2];
#pragma unroll
    for (int K = 0; K < 2; ++K) {
        const float4 f0 = *(const float4*)&sb[H1 + ar * 272 + (K * 32 + ag * 8) * 4];
        const float4 f1 = *(const float4*)&sb[H1 + ar * 272 + (K * 32 + ag * 8) * 4 + 16];
        union { unsigned u[4]; bf16x8 v; } P;
        P.u[0] = cvt_pk_bf16(f0.x, f0.y);
        P.u[1] = cvt_pk_bf16(f0.z, f0.w);
        P.u[2] = cvt_pk_bf16(f1.x, f1.y);
        P.u[3] = cvt_pk_bf16(f1.z, f1.w);
        a2f[K] = P.v;
    }
    f32x4 c2t[3] = {z4, z4, z4};
#pragma unroll
    for (int K = 0; K < 2; ++K) {
        c2t[0] = __builtin_amdgcn_mfma_f32_16x16x32_bf16(a2f[K], W2[K * 3 + 0], c2t[0], 0, 0, 0);
        c2t[1] = __builtin_amdgcn_mfma_f32_16x16x32_bf16(a2f[K], W2[K * 3 + 1], c2t[1], 0, 0, 0);
        c2t[2] = __builtin_amdgcn_mfma_f32_16x16x32_bf16(a2f[K], W2[K * 3 + 2], c2t[2], 0, 0, 0);
    }
#pragma unroll
    for (int t = 0; t < 3; ++t) {
        const int c = t * 16 + ar;
#pragma unroll
        for (int q = 0; q < 4; ++q) {
            const float th = tanh_fast(c2t[t][q] + b2p[t]);
            const float h = fmaf(g2p[t] * (th - m2p[t]), iv2p[t], be2p[t]);
            *(float*)&sb[H2 + (ag * 4 + q) * 272 + c * 4] = h;
        }
    }

    // layer 3: h2 -> (tanh,BN) -> h3   via MFMA (w3 zero-padded handles k/col tails)
    bf16x8 a3f[2];
#pragma unroll
    for (int K = 0; K < 2; ++K) {
        const float4 f0 = *(const float4*)&sb[H2 + ar * 272 + (K * 32 + ag * 8) * 4];
        const float4 f1 = *(const float4*)&sb[H2 + ar * 272 + (K * 32 + ag * 8) * 4 + 16];
        union { unsigned u[4]; bf16x8 v; } P;
        P.u[0] = cvt_pk_bf16(f0.x, f0.y);
        P.u[1] = cvt_pk_bf16(f0.z, f0.w);
        P.u[2] = cvt_pk_bf16(f1.x, f1.y);
        P.u[3] = cvt_pk_bf16(f1.z, f1.w);
        a3f[K] = P.v;
    }
    f32x4 c3t[2] = {z4, z4};
#pragma unroll
    for (int K = 0; K < 2; ++K) {
        c3t[0] = __builtin_amdgcn_mfma_f32_16x16x32_bf16(a3f[K], W3[K * 2 + 0], c3t[0], 0, 0, 0);
        c3t[1] = __builtin_amdgcn_mfma_f32_16x16x32_bf16(a3f[K], W3[K * 2 + 1], c3t[1], 0, 0, 0);
    }
    // tanh+BN3, weighted col-sum (wo1=0 masks cols>=24), 16-lane tree reduce
    float contrib[4];
#pragma unroll
    for (int q = 0; q < 4; ++q) {
        const float t0 = tanh_fast(c3t[0][q] + b3p[0]);
        const float h0 = fmaf(g3p[0] * (t0 - m3p[0]), iv3p[0], be3p[0]);
        const float t1 = tanh_fast(c3t[1][q] + b3p[1]);
        const float h1v = fmaf(g3p[1] * (t1 - m3p[1]), iv3p[1], be3p[1]);
        contrib[q] = h0 * wo0 + h1v * wo1;
    }
#pragma unroll
    for (int m = 1; m < 16; m <<= 1) {
#pragma unroll
        for (int q = 0; q < 4; ++q) contrib[q] += __shfl_xor(contrib[q], m, 64);
    }

    // cross recurrence + sigmoid + store (lane ar==q writes row ag*4+q)
#pragma unroll
    for (int q = 0; q < 4; ++q) {
        const f32x4 pr = *(const f32x4*)&sb[LC + (ag * 4 + q) * 16];
        const float p1 = pr[0], p2 = pr[1], p3 = pr[2], d0 = pr[3];
        const float s1 = p1;
        const float s2 = fmaf(1.f + s1, p2, q2c);
        const float s3 = fmaf(1.f + s1 + s2, p3, q3c);
        const float alpha = 1.f + s1 + s2 + s3;
        const float z = fmaf(alpha, d0, Ccc) + contrib[q] + bo;
        const float o = sigmoid_fast(z);
        if (ar == q) out[myrow0 + ag * 4 + q] = o;
    }
}

extern "C" void kernel_launch(void* const* d_in, const int* in_sizes, int n_in,
                              void* d_out, int out_size, void* d_ws, size_t ws_size,
                              hipStream_t stream) {
    const float* x       = (const float*)d_in[0];
    const float* cross_w = (const float*)d_in[1];
    const float* cross_b = (const float*)d_in[2];
    const float* w1      = (const float*)d_in[3];
    const float* b1      = (const float*)d_in[4];
    const float* g1      = (const float*)d_in[5];
    const float* be1     = (const float*)d_in[6];
    const float* m1      = (const float*)d_in[7];
    const float* v1      = (const float*)d_in[8];
    const float* w2      = (const float*)d_in[9];
    const float* b2      = (const float*)d_in[10];
    const float* g2      = (const float*)d_in[11];
    const float* be2     = (const float*)d_in[12];
    const float* m2      = (const float*)d_in[13];
    const float* v2      = (const float*)d_in[14];
    const float* w3      = (const float*)d_in[15];
    const float* b3      = (const float*)d_in[16];
    const float* g3      = (const float*)d_in[17];
    const float* be3     = (const float*)d_in[18];
    const float* m3      = (const float*)d_in[19];
    const float* v3      = (const float*)d_in[20];
    const float* w_out   = (const float*)d_in[21];
    const float* b_out   = (const float*)d_in[22];
    float* out = (float*)d_out;

    unsigned short* ws = (unsigned short*)d_ws;
    const unsigned short* w2f = (const unsigned short*)((char*)d_ws + WB2_OFF);
    const unsigned short* w3f = (const unsigned short*)((char*)d_ws + WB3_OFF);
    const float* consts = (const float*)((char*)d_ws + CST_OFF);

    dcn_prep<<<44, 256, 0, stream>>>(w1, cross_w, cross_b, w_out, w2, w3, ws);
    dcn_main<<<512, 128, 0, stream>>>(x, ws, w2f, w3f, consts,
                                      b1, g1, be1, m1, v1,
                                      b2, g2, be2, m2, v2,
                                      b3, g3, be3, m3, v3,
                                      w_out, b_out, out);
}